// Round 2
// baseline (856.177 us; speedup 1.0000x reference)
//
#include <hip/hip_runtime.h>
#include <math.h>

#define B_N 4096
#define C_N 100
#define D_N 384
#define EPSF 1e-12f
#define NT 4      // class tiles
#define CT 25     // classes per tile

// ---------------- prep: w2 = 2^cw ; scatter present[targets[i]] = 1 (present pre-zeroed)
__global__ __launch_bounds__(128) void k_prep(const float* __restrict__ cw,
                                              float* __restrict__ w2,
                                              const int* __restrict__ targets,
                                              int* __restrict__ present) {
    int c = blockIdx.x, t = threadIdx.x;
    for (int d = t; d < D_N; d += 128) w2[c * D_N + d] = exp2f(cw[c * D_N + d]);
    int idx = c * 128 + t;               // 100*128 = 12800 >= 4096
    if (idx < B_N) present[targets[idx]] = 1;
}

// ---------------- centers_dist[i] = min_{j != i} sqrt(max(sum_d w2[i,d]*(c[i,d]-c[j,d])^2, 0))
__global__ __launch_bounds__(128) void k_cdist(const float* __restrict__ centers,
                                               const float* __restrict__ w2,
                                               float* __restrict__ cdist) {
    int i = blockIdx.x, j = threadIdx.x;
    float v = INFINITY;
    if (j < C_N && j != i) {
        float acc = 0.f;
        const float4* ci = (const float4*)(centers + i * D_N);
        const float4* cj = (const float4*)(centers + j * D_N);
        const float4* wi = (const float4*)(w2 + i * D_N);
        for (int k = 0; k < D_N / 4; k++) {
            float4 a = ci[k], b = cj[k], w = wi[k];
            float d;
            d = a.x - b.x; acc = fmaf(w.x * d, d, acc);
            d = a.y - b.y; acc = fmaf(w.y * d, d, acc);
            d = a.z - b.z; acc = fmaf(w.z * d, d, acc);
            d = a.w - b.w; acc = fmaf(w.w * d, d, acc);
        }
        v = sqrtf(fmaxf(acc, 0.f));
    }
    for (int m = 1; m < 64; m <<= 1) v = fminf(v, __shfl_xor(v, m, 64));
    __shared__ float s[2];
    if ((j & 63) == 0) s[j >> 6] = v;
    __syncthreads();
    if (j == 0) cdist[i] = fminf(s[0], s[1]);
}

// ---------------- main: block = 16 rows x 25 classes; wave w owns classes c0+w+4j.
// lane: r = l&15 (row), seg = l>>4 (dim quarter, 16-dim interleave -> coalesced class loads)
__global__ __launch_bounds__(256, 4) void k_main(const float* __restrict__ inputs,
                                                 const int* __restrict__ targets,
                                                 const float* __restrict__ w2,
                                                 const float* __restrict__ centers,
                                                 const int* __restrict__ present,
                                                 float2* __restrict__ apan) {
    int tid = threadIdx.x;
    int w   = tid >> 6;          // wave 0..3
    int l   = tid & 63;
    int r   = l & 15;
    int seg = l >> 4;
    int rowtile = blockIdx.x >> 2;
    int ctile   = blockIdx.x & 3;
    int row = rowtile * 16 + r;
    int ti  = targets[row];
    int c0  = ctile * CT;
    int nc  = (w == 0) ? 7 : 6;  // 25 = 7+6+6+6

    const float* xbase = inputs + (size_t)row * D_N + seg * 4;

    float acc[7];
#pragma unroll
    for (int j = 0; j < 7; j++) acc[j] = 0.f;

#pragma unroll
    for (int p = 0; p < 2; p++) {
        float4 xv[12];
#pragma unroll
        for (int k = 0; k < 12; k++)
            xv[k] = *(const float4*)(xbase + (p * 12 + k) * 16);
#pragma unroll
        for (int j = 0; j < 7; j++) {
            if (j < nc) {
                int c = c0 + w + 4 * j;
                const float* wb = w2 + c * D_N + seg * 4;
                const float* cb = centers + c * D_N + seg * 4;
                float a = acc[j];
#pragma unroll
                for (int k = 0; k < 12; k++) {
                    float4 wv = *(const float4*)(wb + (p * 12 + k) * 16);
                    float4 cv = *(const float4*)(cb + (p * 12 + k) * 16);
                    float4 x  = xv[k];
                    float d;
                    d = cv.x - x.x; a = fmaf(wv.x * d, d, a);
                    d = cv.y - x.y; a = fmaf(wv.y * d, d, a);
                    d = cv.z - x.z; a = fmaf(wv.z * d, d, a);
                    d = cv.w - x.w; a = fmaf(wv.w * d, d, a);
                }
                acc[j] = a;
            }
        }
    }

    float vap = -INFINITY, vmin = INFINITY;
#pragma unroll
    for (int j = 0; j < 7; j++) {
        if (j < nc) {
            int c = c0 + w + 4 * j;
            float s = acc[j];
            s += __shfl_xor(s, 16, 64);
            s += __shfl_xor(s, 32, 64);
            float g = sqrtf(fmaxf(s, EPSF));
            if (c == ti) vap = g;
            else if (present[c]) vmin = fminf(vmin, g);
        }
    }

    __shared__ float sap[4][16], san[4][16];
    if (l < 16) { sap[w][r] = vap; san[w][r] = vmin; }
    __syncthreads();
    if (tid < 16) {
        float ap = fmaxf(fmaxf(sap[0][tid], sap[1][tid]), fmaxf(sap[2][tid], sap[3][tid]));
        float an = fminf(fminf(san[0][tid], san[1][tid]), fminf(san[2][tid], san[3][tid]));
        apan[(size_t)ctile * B_N + rowtile * 16 + tid] = make_float2(ap, an);
    }
}

// ---------------- final: combine class tiles, compute loss, reduce sum
__global__ __launch_bounds__(1024) void k_final(const float2* __restrict__ apan,
                                                const float* __restrict__ cdist,
                                                const int* __restrict__ targets,
                                                float* __restrict__ out) {
    int tid = threadIdx.x;
    float sum = 0.f;
    for (int row = tid; row < B_N; row += 1024) {
        float ap = -INFINITY, an = INFINITY;
#pragma unroll
        for (int t = 0; t < NT; t++) {
            float2 v = apan[(size_t)t * B_N + row];
            ap = fmaxf(ap, v.x);
            an = fminf(an, v.y);
        }
        float cc = cdist[targets[row]];
        sum += (an >= cc) ? ap : (ap - an + cc);
    }
    for (int m = 1; m < 64; m <<= 1) sum += __shfl_xor(sum, m, 64);
    __shared__ float sw[16];
    if ((tid & 63) == 0) sw[tid >> 6] = sum;
    __syncthreads();
    if (tid < 64) {
        float v = (tid < 16) ? sw[tid] : 0.f;
        for (int m = 1; m < 16; m <<= 1) v += __shfl_xor(v, m, 64);
        if (tid == 0) out[0] = v / (float)B_N;
    }
}

extern "C" void kernel_launch(void* const* d_in, const int* in_sizes, int n_in,
                              void* d_out, int out_size, void* d_ws, size_t ws_size,
                              hipStream_t stream) {
    const float* inputs  = (const float*)d_in[0];
    const float* centers = (const float*)d_in[1];
    const float* cw      = (const float*)d_in[2];
    const int*   targets = (const int*)d_in[3];
    (void)in_sizes; (void)n_in; (void)out_size; (void)ws_size;

    char* ws = (char*)d_ws;
    float*  w2      = (float*)(ws + 0);         // 100*384*4   = 153600 B
    float2* apan    = (float2*)(ws + 153600);   // 4*4096*8    = 131072 B
    float*  cdist   = (float*)(ws + 284672);    // 100*4
    int*    present = (int*)(ws + 285184);      // 100*4

    hipMemsetAsync(present, 0, C_N * sizeof(int), stream);
    k_prep<<<C_N, 128, 0, stream>>>(cw, w2, targets, present);
    k_cdist<<<C_N, 128, 0, stream>>>(centers, w2, cdist);
    k_main<<<1024, 256, 0, stream>>>(inputs, targets, w2, centers, present, apan);
    k_final<<<1, 1024, 0, stream>>>(apan, cdist, targets, (float*)d_out);
}

// Round 3
// 77.831 us; speedup vs baseline: 11.0004x; 11.0004x over previous
//
#include <hip/hip_runtime.h>
#include <math.h>

#define B_N 4096
#define C_N 100
#define D_N 384
#define EPSF 1e-12f
#define NT 4      // class tiles
#define CT 25     // classes per tile

// ---------------- prep: w2 = 2^cw ; scatter present[targets[i]] = 1 (present pre-zeroed)
__global__ __launch_bounds__(128) void k_prep(const float* __restrict__ cw,
                                              float* __restrict__ w2,
                                              const int* __restrict__ targets,
                                              int* __restrict__ present) {
    int c = blockIdx.x, t = threadIdx.x;
    for (int d = t; d < D_N; d += 128) w2[c * D_N + d] = exp2f(cw[c * D_N + d]);
    int idx = c * 128 + t;               // 100*128 = 12800 >= 4096
    if (idx < B_N) present[targets[idx]] = 1;
}

// ---------------- centers_dist[i] = min_{j != i} sqrt(max(sum_d w2[i,d]*(c[i,d]-c[j,d])^2, 0))
__global__ __launch_bounds__(128) void k_cdist(const float* __restrict__ centers,
                                               const float* __restrict__ w2,
                                               float* __restrict__ cdist) {
    int i = blockIdx.x, j = threadIdx.x;
    float v = INFINITY;
    if (j < C_N && j != i) {
        float acc = 0.f;
        const float4* ci = (const float4*)(centers + i * D_N);
        const float4* cj = (const float4*)(centers + j * D_N);
        const float4* wi = (const float4*)(w2 + i * D_N);
        for (int k = 0; k < D_N / 4; k++) {
            float4 a = ci[k], b = cj[k], w = wi[k];
            float d;
            d = a.x - b.x; acc = fmaf(w.x * d, d, acc);
            d = a.y - b.y; acc = fmaf(w.y * d, d, acc);
            d = a.z - b.z; acc = fmaf(w.z * d, d, acc);
            d = a.w - b.w; acc = fmaf(w.w * d, d, acc);
        }
        v = sqrtf(fmaxf(acc, 0.f));
    }
    for (int m = 1; m < 64; m <<= 1) v = fminf(v, __shfl_xor(v, m, 64));
    __shared__ float s[2];
    if ((j & 63) == 0) s[j >> 6] = v;
    __syncthreads();
    if (j == 0) cdist[i] = fminf(s[0], s[1]);
}

// ---------------- main: block = 16 rows x 25 classes; wave w owns classes c0+w+4j.
// lane: r = l&15 (row), seg = l>>4 (dim quarter, 16-dim interleave -> coalesced class loads)
__global__ __launch_bounds__(256, 2) void k_main(const float* __restrict__ inputs,
                                                 const int* __restrict__ targets,
                                                 const float* __restrict__ w2,
                                                 const float* __restrict__ centers,
                                                 const int* __restrict__ present,
                                                 float2* __restrict__ apan) {
    int tid = threadIdx.x;
    int w   = tid >> 6;          // wave 0..3
    int l   = tid & 63;
    int r   = l & 15;
    int seg = l >> 4;
    int rowtile = blockIdx.x >> 2;
    int ctile   = blockIdx.x & 3;
    int row = rowtile * 16 + r;
    int ti  = targets[row];
    int c0  = ctile * CT;
    int nc  = (w == 0) ? 7 : 6;  // 25 = 7+6+6+6

    const float* xbase = inputs + (size_t)row * D_N + seg * 4;

    float acc[7];
#pragma unroll
    for (int j = 0; j < 7; j++) acc[j] = 0.f;

    // 24 k-steps total (each covers 16 dims for this seg-lane), 3 passes x 8
#pragma unroll
    for (int p = 0; p < 3; p++) {
        float4 xv[8];
#pragma unroll
        for (int k = 0; k < 8; k++)
            xv[k] = *(const float4*)(xbase + (p * 8 + k) * 16);
#pragma unroll
        for (int j = 0; j < 7; j++) {
            if (j < nc) {
                int c = c0 + w + 4 * j;
                const float* wb = w2 + c * D_N + seg * 4;
                const float* cb = centers + c * D_N + seg * 4;
                float a = acc[j];
#pragma unroll
                for (int k = 0; k < 8; k++) {
                    float4 wv = *(const float4*)(wb + (p * 8 + k) * 16);
                    float4 cv = *(const float4*)(cb + (p * 8 + k) * 16);
                    float4 x  = xv[k];
                    float d;
                    d = cv.x - x.x; a = fmaf(wv.x * d, d, a);
                    d = cv.y - x.y; a = fmaf(wv.y * d, d, a);
                    d = cv.z - x.z; a = fmaf(wv.z * d, d, a);
                    d = cv.w - x.w; a = fmaf(wv.w * d, d, a);
                }
                acc[j] = a;
            }
        }
    }

    float vap = -INFINITY, vmin = INFINITY;
#pragma unroll
    for (int j = 0; j < 7; j++) {
        if (j < nc) {
            int c = c0 + w + 4 * j;
            float s = acc[j];
            s += __shfl_xor(s, 16, 64);
            s += __shfl_xor(s, 32, 64);
            float g = sqrtf(fmaxf(s, EPSF));
            if (c == ti) vap = g;
            else if (present[c]) vmin = fminf(vmin, g);
        }
    }

    __shared__ float sap[4][16], san[4][16];
    if (l < 16) { sap[w][r] = vap; san[w][r] = vmin; }
    __syncthreads();
    if (tid < 16) {
        float ap = fmaxf(fmaxf(sap[0][tid], sap[1][tid]), fmaxf(sap[2][tid], sap[3][tid]));
        float an = fminf(fminf(san[0][tid], san[1][tid]), fminf(san[2][tid], san[3][tid]));
        apan[(size_t)ctile * B_N + rowtile * 16 + tid] = make_float2(ap, an);
    }
}

// ---------------- final: combine class tiles, compute loss, reduce sum
__global__ __launch_bounds__(1024) void k_final(const float2* __restrict__ apan,
                                                const float* __restrict__ cdist,
                                                const int* __restrict__ targets,
                                                float* __restrict__ out) {
    int tid = threadIdx.x;
    float sum = 0.f;
    for (int row = tid; row < B_N; row += 1024) {
        float ap = -INFINITY, an = INFINITY;
#pragma unroll
        for (int t = 0; t < NT; t++) {
            float2 v = apan[(size_t)t * B_N + row];
            ap = fmaxf(ap, v.x);
            an = fminf(an, v.y);
        }
        float cc = cdist[targets[row]];
        sum += (an >= cc) ? ap : (ap - an + cc);
    }
    for (int m = 1; m < 64; m <<= 1) sum += __shfl_xor(sum, m, 64);
    __shared__ float sw[16];
    if ((tid & 63) == 0) sw[tid >> 6] = sum;
    __syncthreads();
    if (tid < 64) {
        float v = (tid < 16) ? sw[tid] : 0.f;
        for (int m = 1; m < 16; m <<= 1) v += __shfl_xor(v, m, 64);
        if (tid == 0) out[0] = v / (float)B_N;
    }
}

extern "C" void kernel_launch(void* const* d_in, const int* in_sizes, int n_in,
                              void* d_out, int out_size, void* d_ws, size_t ws_size,
                              hipStream_t stream) {
    const float* inputs  = (const float*)d_in[0];
    const float* centers = (const float*)d_in[1];
    const float* cw      = (const float*)d_in[2];
    const int*   targets = (const int*)d_in[3];
    (void)in_sizes; (void)n_in; (void)out_size; (void)ws_size;

    char* ws = (char*)d_ws;
    float*  w2      = (float*)(ws + 0);         // 100*384*4   = 153600 B
    float2* apan    = (float2*)(ws + 153600);   // 4*4096*8    = 131072 B
    float*  cdist   = (float*)(ws + 284672);    // 100*4
    int*    present = (int*)(ws + 285184);      // 100*4

    hipMemsetAsync(present, 0, C_N * sizeof(int), stream);
    k_prep<<<C_N, 128, 0, stream>>>(cw, w2, targets, present);
    k_cdist<<<C_N, 128, 0, stream>>>(centers, w2, cdist);
    k_main<<<1024, 256, 0, stream>>>(inputs, targets, w2, centers, present, apan);
    k_final<<<1, 1024, 0, stream>>>(apan, cdist, targets, (float*)d_out);
}

// Round 4
// 73.857 us; speedup vs baseline: 11.5924x; 1.0538x over previous
//
#include <hip/hip_runtime.h>
#include <math.h>

#define B_N 4096
#define C_N 100
#define D_N 384
#define EPSF 1e-12f
#define NT 4      // class tiles
#define CT 25     // classes per tile

// ---------------- prep: w2 = 2^cw, wc = w2*centers, a2[c] = sum wc*centers;
// also scatter present[targets[i]] = 1 (present pre-zeroed by memset)
__global__ __launch_bounds__(128) void k_prep(const float* __restrict__ centers,
                                              const float* __restrict__ cw,
                                              float* __restrict__ w2,
                                              float* __restrict__ wc,
                                              float* __restrict__ a2,
                                              const int* __restrict__ targets,
                                              int* __restrict__ present) {
    int c = blockIdx.x, t = threadIdx.x;
    float acc = 0.f;
    for (int d = t; d < D_N; d += 128) {
        float wv = exp2f(cw[c * D_N + d]);
        float ce = centers[c * D_N + d];
        float p  = wv * ce;
        w2[c * D_N + d] = wv;
        wc[c * D_N + d] = p;
        acc = fmaf(p, ce, acc);
    }
    for (int m = 1; m < 64; m <<= 1) acc += __shfl_xor(acc, m, 64);
    __shared__ float s[2];
    if ((t & 63) == 0) s[t >> 6] = acc;
    __syncthreads();
    if (t == 0) a2[c] = s[0] + s[1];
    int idx = c * 128 + t;               // 100*128 = 12800 >= 4096
    if (idx < B_N) present[targets[idx]] = 1;
}

// ---------------- centers_dist[i] = min_{j != i} sqrt(max(sum_d w2[i,d]*(c[i,d]-c[j,d])^2, 0))
__global__ __launch_bounds__(128) void k_cdist(const float* __restrict__ centers,
                                               const float* __restrict__ w2,
                                               float* __restrict__ cdist) {
    int i = blockIdx.x, j = threadIdx.x;
    float v = INFINITY;
    if (j < C_N && j != i) {
        float acc = 0.f;
        const float4* ci = (const float4*)(centers + i * D_N);
        const float4* cj = (const float4*)(centers + j * D_N);
        const float4* wi = (const float4*)(w2 + i * D_N);
        for (int k = 0; k < D_N / 4; k++) {
            float4 a = ci[k], b = cj[k], w = wi[k];
            float d;
            d = a.x - b.x; acc = fmaf(w.x * d, d, acc);
            d = a.y - b.y; acc = fmaf(w.y * d, d, acc);
            d = a.z - b.z; acc = fmaf(w.z * d, d, acc);
            d = a.w - b.w; acc = fmaf(w.w * d, d, acc);
        }
        v = sqrtf(fmaxf(acc, 0.f));
    }
    for (int m = 1; m < 64; m <<= 1) v = fminf(v, __shfl_xor(v, m, 64));
    __shared__ float s[2];
    if ((j & 63) == 0) s[j >> 6] = v;
    __syncthreads();
    if (j == 0) cdist[i] = fminf(s[0], s[1]);
}

// ---------------- main: block = 16 rows x 25 classes; wave w owns classes c0+w+4j.
// lane: r = l&15 (row), seg = l>>4 (dim quarter, 16-dim interleave -> coalesced class loads)
// k OUTER, j INNER: 14 independent accumulator chains per wave -> issue-bound, not latency-bound.
__global__ __launch_bounds__(256, 2) void k_main(const float* __restrict__ inputs,
                                                 const int* __restrict__ targets,
                                                 const float* __restrict__ w2,
                                                 const float* __restrict__ wc,
                                                 const float* __restrict__ a2,
                                                 const int* __restrict__ present,
                                                 float2* __restrict__ apan) {
    int tid = threadIdx.x;
    int w   = tid >> 6;          // wave 0..3
    int l   = tid & 63;
    int r   = l & 15;
    int seg = l >> 4;
    int rowtile = blockIdx.x >> 2;
    int ctile   = blockIdx.x & 3;
    int row = rowtile * 16 + r;
    int ti  = targets[row];
    int c0  = ctile * CT;
    int nc  = (w == 0) ? 7 : 6;  // 25 = 7+6+6+6

    const float* xb  = inputs + (size_t)row * D_N + seg * 4;
    const float* wcb = wc + (size_t)(c0 + w) * D_N + seg * 4;
    const float* w2b = w2 + (size_t)(c0 + w) * D_N + seg * 4;

    float cr[7], qd[7];
#pragma unroll
    for (int j = 0; j < 7; j++) { cr[j] = 0.f; qd[j] = 0.f; }

#pragma unroll
    for (int k = 0; k < D_N / 16; k++) {        // 24 k-steps, 16 dims each (4 segs x 4)
        float4 x = *(const float4*)(xb + k * 16);
        float4 x2 = make_float4(x.x * x.x, x.y * x.y, x.z * x.z, x.w * x.w);
#pragma unroll
        for (int j = 0; j < 7; j++) {
            if (j < nc) {
                float4 wcv = *(const float4*)(wcb + (size_t)j * 4 * D_N + k * 16);
                float4 w2v = *(const float4*)(w2b + (size_t)j * 4 * D_N + k * 16);
                float c1 = cr[j], q1 = qd[j];
                c1 = fmaf(x.x,  wcv.x, c1);
                c1 = fmaf(x.y,  wcv.y, c1);
                c1 = fmaf(x.z,  wcv.z, c1);
                c1 = fmaf(x.w,  wcv.w, c1);
                q1 = fmaf(x2.x, w2v.x, q1);
                q1 = fmaf(x2.y, w2v.y, q1);
                q1 = fmaf(x2.z, w2v.z, q1);
                q1 = fmaf(x2.w, w2v.w, q1);
                cr[j] = c1; qd[j] = q1;
            }
        }
    }

    float vap = -INFINITY, vmin = INFINITY;
#pragma unroll
    for (int j = 0; j < 7; j++) {
        if (j < nc) {
            int c = c0 + w + 4 * j;
            float scr = cr[j];
            scr += __shfl_xor(scr, 16, 64);
            scr += __shfl_xor(scr, 32, 64);
            float sqd = qd[j];
            sqd += __shfl_xor(sqd, 16, 64);
            sqd += __shfl_xor(sqd, 32, 64);
            float d2 = a2[c] - 2.f * scr + sqd;
            float g  = sqrtf(fmaxf(d2, EPSF));
            if (c == ti) vap = g;
            else if (present[c]) vmin = fminf(vmin, g);
        }
    }

    __shared__ float sap[4][16], san[4][16];
    if (l < 16) { sap[w][r] = vap; san[w][r] = vmin; }
    __syncthreads();
    if (tid < 16) {
        float ap = fmaxf(fmaxf(sap[0][tid], sap[1][tid]), fmaxf(sap[2][tid], sap[3][tid]));
        float an = fminf(fminf(san[0][tid], san[1][tid]), fminf(san[2][tid], san[3][tid]));
        apan[(size_t)ctile * B_N + rowtile * 16 + tid] = make_float2(ap, an);
    }
}

// ---------------- final: combine class tiles, compute loss, reduce sum
__global__ __launch_bounds__(1024) void k_final(const float2* __restrict__ apan,
                                                const float* __restrict__ cdist,
                                                const int* __restrict__ targets,
                                                float* __restrict__ out) {
    int tid = threadIdx.x;
    float sum = 0.f;
    for (int row = tid; row < B_N; row += 1024) {
        float ap = -INFINITY, an = INFINITY;
#pragma unroll
        for (int t = 0; t < NT; t++) {
            float2 v = apan[(size_t)t * B_N + row];
            ap = fmaxf(ap, v.x);
            an = fminf(an, v.y);
        }
        float cc = cdist[targets[row]];
        sum += (an >= cc) ? ap : (ap - an + cc);
    }
    for (int m = 1; m < 64; m <<= 1) sum += __shfl_xor(sum, m, 64);
    __shared__ float sw[16];
    if ((tid & 63) == 0) sw[tid >> 6] = sum;
    __syncthreads();
    if (tid < 64) {
        float v = (tid < 16) ? sw[tid] : 0.f;
        for (int m = 1; m < 16; m <<= 1) v += __shfl_xor(v, m, 64);
        if (tid == 0) out[0] = v / (float)B_N;
    }
}

extern "C" void kernel_launch(void* const* d_in, const int* in_sizes, int n_in,
                              void* d_out, int out_size, void* d_ws, size_t ws_size,
                              hipStream_t stream) {
    const float* inputs  = (const float*)d_in[0];
    const float* centers = (const float*)d_in[1];
    const float* cw      = (const float*)d_in[2];
    const int*   targets = (const int*)d_in[3];
    (void)in_sizes; (void)n_in; (void)out_size; (void)ws_size;

    char* ws = (char*)d_ws;
    float*  w2      = (float*)(ws + 0);         // 100*384*4 = 153600 B
    float*  wc      = (float*)(ws + 153600);    // 100*384*4 = 153600 B
    float2* apan    = (float2*)(ws + 307200);   // 4*4096*8  = 131072 B
    float*  a2      = (float*)(ws + 438272);    // 100*4
    float*  cdist   = (float*)(ws + 438784);    // 100*4
    int*    present = (int*)(ws + 439296);      // 100*4

    hipMemsetAsync(present, 0, C_N * sizeof(int), stream);
    k_prep<<<C_N, 128, 0, stream>>>(centers, cw, w2, wc, a2, targets, present);
    k_cdist<<<C_N, 128, 0, stream>>>(centers, w2, cdist);
    k_main<<<1024, 256, 0, stream>>>(inputs, targets, w2, wc, a2, present, apan);
    k_final<<<1, 1024, 0, stream>>>(apan, cdist, targets, (float*)d_out);
}